// Round 1
// baseline (1346.919 us; speedup 1.0000x reference)
//
#include <hip/hip_runtime.h>
#include <math.h>

#define TT 256
#define HIDDEN 2048
#define NH 16
#define HD 128
#define KDIM 2048
#define NCG 30
#define KSTR 132   // 128 + 4 pad: keeps 16B alignment, spreads LDS banks

__device__ __forceinline__ float wave_sum64(float v) {
#pragma unroll
    for (int off = 32; off > 0; off >>= 1) v += __shfl_xor(v, off, 64);
    return v;
}

// ---------------- f32 GEMM: C[M,N] = A[M,K] @ B[K,N], 64x64 tile ----------------
__device__ __forceinline__ void gemm_tile(const float* __restrict__ A,
                                          const float* __restrict__ B,
                                          float* __restrict__ C,
                                          int K, int N)
{
    __shared__ float As[8][64];
    __shared__ float Bs[8][64];
    const int tx = threadIdx.x, ty = threadIdx.y;
    const int tid = ty * 16 + tx;
    const int m0 = blockIdx.y * 64, n0 = blockIdx.x * 64;
    const int a_row = tid >> 2, a_col = (tid & 3) * 2;
    const int b_row = tid >> 5, b_col = (tid & 31) * 2;
    float acc[4][4] = {};
    for (int k0 = 0; k0 < K; k0 += 8) {
        const float2 av = *(const float2*)&A[(m0 + a_row) * K + k0 + a_col];
        const float2 bv = *(const float2*)&B[(k0 + b_row) * N + n0 + b_col];
        __syncthreads();
        As[a_col][a_row]     = av.x;
        As[a_col + 1][a_row] = av.y;
        Bs[b_row][b_col]     = bv.x;
        Bs[b_row][b_col + 1] = bv.y;
        __syncthreads();
#pragma unroll
        for (int kk = 0; kk < 8; kk++) {
            const float4 a4 = *(const float4*)&As[kk][ty * 4];
            const float4 b4 = *(const float4*)&Bs[kk][tx * 4];
            const float ar[4] = {a4.x, a4.y, a4.z, a4.w};
            const float br[4] = {b4.x, b4.y, b4.z, b4.w};
#pragma unroll
            for (int i = 0; i < 4; i++)
#pragma unroll
                for (int j = 0; j < 4; j++)
                    acc[i][j] = fmaf(ar[i], br[j], acc[i][j]);
        }
    }
#pragma unroll
    for (int i = 0; i < 4; i++) {
        float4 o4 = make_float4(acc[i][0], acc[i][1], acc[i][2], acc[i][3]);
        *(float4*)&C[(m0 + ty * 4 + i) * N + n0 + tx * 4] = o4;
    }
}

__global__ __launch_bounds__(256) void gemm_qkv_kernel(
    const float* __restrict__ X,
    const float* __restrict__ Wq, const float* __restrict__ Wk, const float* __restrict__ Wv,
    float* __restrict__ Cq, float* __restrict__ Ck, float* __restrict__ Cv)
{
    const float* B = (blockIdx.z == 0) ? Wq : (blockIdx.z == 1) ? Wk : Wv;
    float* C = (blockIdx.z == 0) ? Cq : (blockIdx.z == 1) ? Ck : Cv;
    gemm_tile(X, B, C, HIDDEN, KDIM);
}

__global__ __launch_bounds__(256) void gemm_out_kernel(
    const float* __restrict__ A, const float* __restrict__ Wo, float* __restrict__ C)
{
    gemm_tile(A, Wo, C, KDIM, HIDDEN);
}

// ---------------- per-t small projections: g = logsigmoid(xWa+ba), beta = sigmoid(xWb+bb) ---
__global__ __launch_bounds__(256) void ab_kernel(
    const float* __restrict__ X, const float* __restrict__ Wa, const float* __restrict__ ba,
    const float* __restrict__ Wb, const float* __restrict__ bb,
    float* __restrict__ g, float* __restrict__ beta)
{
    const int t = blockIdx.x;
    const int lane = threadIdx.x & 63, w = threadIdx.x >> 6;
    for (int oi = 0; oi < 8; oi++) {
        const int o = w * 8 + oi;
        const int h = o & 15, which = o >> 4;
        const float* W = which ? Wb : Wa;
        float acc = 0.f;
#pragma unroll 4
        for (int i = 0; i < 32; i++) {
            const int kk = lane + 64 * i;
            acc = fmaf(X[t * HIDDEN + kk], W[kk * NH + h], acc);
        }
        acc = wave_sum64(acc);
        if (lane == 0) {
            if (which == 0) {
                float z = acc + ba[h];
                g[t * NH + h] = fminf(z, 0.f) - log1pf(__expf(-fabsf(z)));
            } else {
                float z = acc + bb[h];
                beta[t * NH + h] = 1.f / (1.f + __expf(-z));
            }
        }
    }
}

__global__ void cumsum_kernel(const float* __restrict__ g, float* __restrict__ G) {
    const int h = threadIdx.x;
    if (h < NH) {
        float run = 0.f;
        for (int t = 0; t < TT; t++) { run += g[t * NH + h]; G[t * NH + h] = run; }
    }
}

__global__ void lamb_kernel(const float* __restrict__ lp, float* __restrict__ lamb) {
    const int i = blockIdx.x * 256 + threadIdx.x;
    if (i < KDIM) {
        float x = lp[i];
        lamb[i] = fmaxf(x, 0.f) + log1pf(__expf(-fabsf(x))) + 0.25f;  // softplus + 0.25
    }
}

// ---------------- causal depthwise conv(4) + silu + per-head l2norm ----------------
__global__ __launch_bounds__(128) void conv_silu_l2_kernel(
    const float* __restrict__ q_pre, const float* __restrict__ k_pre,
    const float* __restrict__ cwq, const float* __restrict__ cwk,
    float* __restrict__ qn, float* __restrict__ kn)
{
    const int t = blockIdx.x, h = blockIdx.y, which = blockIdx.z;
    const int d = threadIdx.x;
    const int c = h * HD + d;
    const float* pre = which ? k_pre : q_pre;
    const float* cw  = which ? cwk : cwq;
    float y = 0.f;
#pragma unroll
    for (int i = 0; i < 4; i++) {
        const int ts = t - 3 + i;
        if (ts >= 0) y = fmaf(pre[ts * KDIM + c], cw[c * 4 + i], y);
    }
    const float s = y / (1.f + __expf(-y));  // silu
    float v = s * s;
#pragma unroll
    for (int off = 32; off > 0; off >>= 1) v += __shfl_down(v, off, 64);
    __shared__ float red[2];
    if ((threadIdx.x & 63) == 0) red[threadIdx.x >> 6] = v;
    __syncthreads();
    const float sum = red[0] + red[1];
    float* dst = which ? kn : qn;
    dst[t * KDIM + c] = s * rsqrtf(sum + 1e-6f);
}

// ---------------- mesa recurrence: independent CG solve per (t,h) ----------------
// A_t p = lamb .* p + sum_{s<=t} w_s(t) (k_s . p) k_s,  w_s(t) = beta_s*exp(G_t - G_s)
// o_t   = sum_{s<=t} w_s(t) (k_s . x*) v_s
__global__ __launch_bounds__(256) void mesa_kernel(
    const float* __restrict__ qn, const float* __restrict__ kn, const float* __restrict__ vv,
    const float* __restrict__ G, const float* __restrict__ beta, const float* __restrict__ lamb,
    float* __restrict__ o)
{
    extern __shared__ float smem[];
    float* Ksh = smem;                       // 256*KSTR
    float* psh = Ksh + 256 * KSTR;           // 4*128
    float* ysh = psh + 4 * 128;              // 4*256
    float* Gsh = ysh + 4 * 256;              // 256
    float* Bsh = Gsh + 256;                  // 256
    float* lsh = Bsh + 256;                  // 128

    const int h = blockIdx.x, grp = blockIdx.y;
    const int tid = threadIdx.x, lane = tid & 63, w = tid >> 6;

    // stage K[h] rows coalesced (row = t, 128 floats)
    for (int i = tid; i < 256 * 32; i += 256) {
        const int row = i >> 5, c4 = (i & 31) << 2;
        const float4 kv = *(const float4*)&kn[(row * NH + h) * HD + c4];
        *(float4*)&Ksh[row * KSTR + c4] = kv;
    }
    Gsh[tid] = G[tid * NH + h];
    Bsh[tid] = beta[tid * NH + h];
    if (tid < HD) lsh[tid] = lamb[h * HD + tid];
    __syncthreads();

    const int slot = grp * 4 + w;
    float* myp = psh + w * 128;
    float* myy = ysh + w * 256;
    const int d0 = lane * 2, d1 = lane * 2 + 1;

    for (int j = 0; j < 4; j++) {
        const int t = 64 * j + ((j & 1) ? (63 - slot) : slot);
        const float Gt = Gsh[t];
        const int mmax = t >> 6;

        const float2 b2 = *(const float2*)&qn[(t * NH + h) * HD + d0];
        float x0 = 0.f, x1 = 0.f;
        float r0 = b2.x, r1 = b2.y, p0 = r0, p1 = r1;
        myp[d0] = p0; myp[d1] = p1;
        float rs = wave_sum64(r0 * r0 + r1 * r1);

        for (int it = 0; it < NCG; it++) {
            // pass1: y_s = w_s * (k_s . p), lane handles s = lane + 64m
            for (int m = 0; m <= mmax; m++) {
                const int s = lane + 64 * m;
                const float* Kr = Ksh + (lane + 64 * m) * KSTR;
                float a = 0.f;
#pragma unroll 8
                for (int c = 0; c < 128; c += 4) {
                    const float4 pv = *(const float4*)&myp[c];
                    const float4 kv = *(const float4*)&Kr[c];
                    a = fmaf(kv.x, pv.x, a); a = fmaf(kv.y, pv.y, a);
                    a = fmaf(kv.z, pv.z, a); a = fmaf(kv.w, pv.w, a);
                }
                if (s <= t) myy[s] = Bsh[s] * __expf(Gt - Gsh[s]) * a;
            }
            // pass2: Ap = lamb.*p + sum_s y_s * k_s
            float Ap0 = lsh[d0] * p0, Ap1 = lsh[d1] * p1;
#pragma unroll 4
            for (int s = 0; s <= t; s++) {
                const float yv = myy[s];
                const float2 kv = *(const float2*)&Ksh[s * KSTR + d0];
                Ap0 = fmaf(yv, kv.x, Ap0);
                Ap1 = fmaf(yv, kv.y, Ap1);
            }
            const float pAp = wave_sum64(p0 * Ap0 + p1 * Ap1);
            const float alpha = rs / (pAp + 1e-12f);
            x0 = fmaf(alpha, p0, x0); x1 = fmaf(alpha, p1, x1);
            r0 = fmaf(-alpha, Ap0, r0); r1 = fmaf(-alpha, Ap1, r1);
            const float rsn = wave_sum64(r0 * r0 + r1 * r1);
            const float bcg = rsn / (rs + 1e-12f);
            p0 = fmaf(bcg, p0, r0); p1 = fmaf(bcg, p1, r1);
            rs = rsn;
            myp[d0] = p0; myp[d1] = p1;
        }

        // z_s = w_s * (k_s . x)  -> myy
        myp[d0] = x0; myp[d1] = x1;
        for (int m = 0; m <= mmax; m++) {
            const int s = lane + 64 * m;
            const float* Kr = Ksh + (lane + 64 * m) * KSTR;
            float a = 0.f;
#pragma unroll 8
            for (int c = 0; c < 128; c += 4) {
                const float4 pv = *(const float4*)&myp[c];
                const float4 kv = *(const float4*)&Kr[c];
                a = fmaf(kv.x, pv.x, a); a = fmaf(kv.y, pv.y, a);
                a = fmaf(kv.z, pv.z, a); a = fmaf(kv.w, pv.w, a);
            }
            if (s <= t) myy[s] = Bsh[s] * __expf(Gt - Gsh[s]) * a;
        }
        // o_t = sum_s z_s * v_s  (V straight from global, L2-resident, coalesced)
        float o0 = 0.f, o1 = 0.f;
#pragma unroll 4
        for (int s = 0; s <= t; s++) {
            const float zv = myy[s];
            const float2 v2 = *(const float2*)&vv[(s * NH + h) * HD + d0];
            o0 = fmaf(zv, v2.x, o0);
            o1 = fmaf(zv, v2.y, o1);
        }
        *(float2*)&o[(t * NH + h) * HD + d0] = make_float2(o0, o1);
    }
}

// ---------------- rmsnorm over D with weight ----------------
__global__ __launch_bounds__(128) void rmsnorm_kernel(const float* __restrict__ o,
                                                      const float* __restrict__ wt,
                                                      float* __restrict__ on)
{
    const int t = blockIdx.x, h = blockIdx.y, d = threadIdx.x;
    const float val = o[(t * NH + h) * HD + d];
    float v = val * val;
#pragma unroll
    for (int off = 32; off > 0; off >>= 1) v += __shfl_down(v, off, 64);
    __shared__ float red[2];
    if ((threadIdx.x & 63) == 0) red[threadIdx.x >> 6] = v;
    __syncthreads();
    const float mean = (red[0] + red[1]) * (1.f / HD);
    on[(t * NH + h) * HD + d] = val * rsqrtf(mean + 1e-5f) * wt[d];
}

extern "C" void kernel_launch(void* const* d_in, const int* in_sizes, int n_in,
                              void* d_out, int out_size, void* d_ws, size_t ws_size,
                              hipStream_t stream)
{
    (void)in_sizes; (void)n_in; (void)out_size; (void)ws_size;
    const float* x   = (const float*)d_in[0];
    const float* Wq  = (const float*)d_in[1];
    const float* Wk  = (const float*)d_in[2];
    const float* Wv  = (const float*)d_in[3];
    const float* Wa  = (const float*)d_in[4];
    const float* ba  = (const float*)d_in[5];
    const float* Wb  = (const float*)d_in[6];
    const float* bb  = (const float*)d_in[7];
    const float* cwq = (const float*)d_in[8];
    const float* cwk = (const float*)d_in[9];
    const float* lp  = (const float*)d_in[10];
    const float* onw = (const float*)d_in[11];
    const float* Wo  = (const float*)d_in[12];

    float* ws    = (float*)d_ws;
    float* q_pre = ws;                  // 524288
    float* k_pre = q_pre + 524288;      // 524288
    float* v     = k_pre + 524288;      // 524288
    float* qn    = v + 524288;          // 524288
    float* kn    = qn + 524288;         // 524288
    float* g     = kn + 524288;         // 4096
    float* beta  = g + 4096;            // 4096
    float* G     = beta + 4096;         // 4096
    float* lamb  = G + 4096;            // 2048
    float* o     = k_pre;               // alias: k_pre dead after conv
    float* onorm = q_pre;               // alias: q_pre dead after conv
    float* outp  = (float*)d_out;

    gemm_qkv_kernel<<<dim3(32, 4, 3), dim3(16, 16), 0, stream>>>(x, Wq, Wk, Wv, q_pre, k_pre, v);
    ab_kernel<<<dim3(TT), dim3(256), 0, stream>>>(x, Wa, ba, Wb, bb, g, beta);
    cumsum_kernel<<<1, 64, 0, stream>>>(g, G);
    lamb_kernel<<<8, 256, 0, stream>>>(lp, lamb);
    conv_silu_l2_kernel<<<dim3(TT, NH, 2), 128, 0, stream>>>(q_pre, k_pre, cwq, cwk, qn, kn);

    const size_t lds_bytes = (size_t)(256 * KSTR + 4 * 128 + 4 * 256 + 256 + 256 + 128) * sizeof(float);
    (void)hipFuncSetAttribute((const void*)mesa_kernel,
                              hipFuncAttributeMaxDynamicSharedMemorySize, (int)lds_bytes);
    mesa_kernel<<<dim3(NH, 16), 256, lds_bytes, stream>>>(qn, kn, v, G, beta, lamb, o);

    rmsnorm_kernel<<<dim3(TT, NH), 128, 0, stream>>>(o, onw, onorm);
    gemm_out_kernel<<<dim3(32, 4, 1), dim3(16, 16), 0, stream>>>(onorm, Wo, outp);
}

// Round 2
// 817.111 us; speedup vs baseline: 1.6484x; 1.6484x over previous
//
#include <hip/hip_runtime.h>
#include <math.h>

#define TT 256
#define HIDDEN 2048
#define NH 16
#define HD 128
#define KDIM 2048
#define NCG 30

// fp16 cg-blocked K layout: [16 cg][256 row][8 halves], group stride 2056 halves
// (4112 B: 1028 dwords ≡ 4 mod 32 banks -> pass2 2-way aliasing = free)
#define CGSTR 2056

typedef _Float16 h2 __attribute__((ext_vector_type(2)));
typedef _Float16 h4 __attribute__((ext_vector_type(4)));

#if defined(__has_builtin)
#if __has_builtin(__builtin_amdgcn_fdot2)
#define HAVE_FDOT2 1
#endif
#endif

__device__ __forceinline__ h2 u2h(unsigned int u) { return __builtin_bit_cast(h2, u); }

__device__ __forceinline__ float fdot2(h2 a, h2 b, float c) {
#ifdef HAVE_FDOT2
    return __builtin_amdgcn_fdot2(a, b, c, false);
#else
    return fmaf((float)a.x, (float)b.x, fmaf((float)a.y, (float)b.y, c));
#endif
}

__device__ __forceinline__ float wave_sum64(float v) {
#pragma unroll
    for (int off = 32; off > 0; off >>= 1) v += __shfl_xor(v, off, 64);
    return v;
}

// ---------------- f32 GEMM: C[M,N] = A[M,K] @ B[K,N], 64x64 tile ----------------
__device__ __forceinline__ void gemm_tile(const float* __restrict__ A,
                                          const float* __restrict__ B,
                                          float* __restrict__ C,
                                          int K, int N)
{
    __shared__ float As[8][64];
    __shared__ float Bs[8][64];
    const int tx = threadIdx.x, ty = threadIdx.y;
    const int tid = ty * 16 + tx;
    const int m0 = blockIdx.y * 64, n0 = blockIdx.x * 64;
    const int a_row = tid >> 2, a_col = (tid & 3) * 2;
    const int b_row = tid >> 5, b_col = (tid & 31) * 2;
    float acc[4][4] = {};
    for (int k0 = 0; k0 < K; k0 += 8) {
        const float2 av = *(const float2*)&A[(m0 + a_row) * K + k0 + a_col];
        const float2 bv = *(const float2*)&B[(k0 + b_row) * N + n0 + b_col];
        __syncthreads();
        As[a_col][a_row]     = av.x;
        As[a_col + 1][a_row] = av.y;
        Bs[b_row][b_col]     = bv.x;
        Bs[b_row][b_col + 1] = bv.y;
        __syncthreads();
#pragma unroll
        for (int kk = 0; kk < 8; kk++) {
            const float4 a4 = *(const float4*)&As[kk][ty * 4];
            const float4 b4 = *(const float4*)&Bs[kk][tx * 4];
            const float ar[4] = {a4.x, a4.y, a4.z, a4.w};
            const float br[4] = {b4.x, b4.y, b4.z, b4.w};
#pragma unroll
            for (int i = 0; i < 4; i++)
#pragma unroll
                for (int j = 0; j < 4; j++)
                    acc[i][j] = fmaf(ar[i], br[j], acc[i][j]);
        }
    }
#pragma unroll
    for (int i = 0; i < 4; i++) {
        float4 o4 = make_float4(acc[i][0], acc[i][1], acc[i][2], acc[i][3]);
        *(float4*)&C[(m0 + ty * 4 + i) * N + n0 + tx * 4] = o4;
    }
}

__global__ __launch_bounds__(256) void gemm_qkv_kernel(
    const float* __restrict__ X,
    const float* __restrict__ Wq, const float* __restrict__ Wk, const float* __restrict__ Wv,
    float* __restrict__ Cq, float* __restrict__ Ck, float* __restrict__ Cv)
{
    const float* B = (blockIdx.z == 0) ? Wq : (blockIdx.z == 1) ? Wk : Wv;
    float* C = (blockIdx.z == 0) ? Cq : (blockIdx.z == 1) ? Ck : Cv;
    gemm_tile(X, B, C, HIDDEN, KDIM);
}

__global__ __launch_bounds__(256) void gemm_out_kernel(
    const float* __restrict__ A, const float* __restrict__ Wo, float* __restrict__ C)
{
    gemm_tile(A, Wo, C, KDIM, HIDDEN);
}

// ---------------- per-t small projections ----------------
__global__ __launch_bounds__(256) void ab_kernel(
    const float* __restrict__ X, const float* __restrict__ Wa, const float* __restrict__ ba,
    const float* __restrict__ Wb, const float* __restrict__ bb,
    float* __restrict__ g, float* __restrict__ beta)
{
    const int t = blockIdx.x;
    const int lane = threadIdx.x & 63, w = threadIdx.x >> 6;
    for (int oi = 0; oi < 8; oi++) {
        const int o = w * 8 + oi;
        const int h = o & 15, which = o >> 4;
        const float* W = which ? Wb : Wa;
        float acc = 0.f;
#pragma unroll 4
        for (int i = 0; i < 32; i++) {
            const int kk = lane + 64 * i;
            acc = fmaf(X[t * HIDDEN + kk], W[kk * NH + h], acc);
        }
        acc = wave_sum64(acc);
        if (lane == 0) {
            if (which == 0) {
                float z = acc + ba[h];
                g[t * NH + h] = fminf(z, 0.f) - log1pf(__expf(-fabsf(z)));
            } else {
                float z = acc + bb[h];
                beta[t * NH + h] = 1.f / (1.f + __expf(-z));
            }
        }
    }
}

__global__ void cumsum_kernel(const float* __restrict__ g, float* __restrict__ G) {
    const int h = threadIdx.x;
    if (h < NH) {
        float run = 0.f;
        for (int t = 0; t < TT; t++) { run += g[t * NH + h]; G[t * NH + h] = run; }
    }
}

__global__ void lamb_kernel(const float* __restrict__ lp, float* __restrict__ lamb) {
    const int i = blockIdx.x * 256 + threadIdx.x;
    if (i < KDIM) {
        float x = lp[i];
        lamb[i] = fmaxf(x, 0.f) + log1pf(__expf(-fabsf(x))) + 0.25f;
    }
}

// ---------------- causal depthwise conv(4) + silu + per-head l2norm ----------------
__global__ __launch_bounds__(128) void conv_silu_l2_kernel(
    const float* __restrict__ q_pre, const float* __restrict__ k_pre,
    const float* __restrict__ cwq, const float* __restrict__ cwk,
    float* __restrict__ qn, float* __restrict__ kn)
{
    const int t = blockIdx.x, h = blockIdx.y, which = blockIdx.z;
    const int d = threadIdx.x;
    const int c = h * HD + d;
    const float* pre = which ? k_pre : q_pre;
    const float* cw  = which ? cwk : cwq;
    float y = 0.f;
#pragma unroll
    for (int i = 0; i < 4; i++) {
        const int ts = t - 3 + i;
        if (ts >= 0) y = fmaf(pre[ts * KDIM + c], cw[c * 4 + i], y);
    }
    const float s = y / (1.f + __expf(-y));
    float v = s * s;
#pragma unroll
    for (int off = 32; off > 0; off >>= 1) v += __shfl_down(v, off, 64);
    __shared__ float red[2];
    if ((threadIdx.x & 63) == 0) red[threadIdx.x >> 6] = v;
    __syncthreads();
    const float sum = red[0] + red[1];
    float* dst = which ? kn : qn;
    dst[t * KDIM + c] = s * rsqrtf(sum + 1e-6f);
}

// ---------------- mesa recurrence: independent CG solve per (t,h) ----------------
// fp16 K in cg-blocked LDS; 512 blocks (2 t per wave, slot + 255-slot pairing)
__global__ __launch_bounds__(256) void mesa_kernel(
    const float* __restrict__ qn, const float* __restrict__ kn, const float* __restrict__ vv,
    const float* __restrict__ G, const float* __restrict__ beta, const float* __restrict__ lamb,
    float* __restrict__ o)
{
    extern __shared__ char smem_raw[];
    _Float16* Ksh = (_Float16*)smem_raw;                 // 16*2056 halves = 65792 B
    float* wsh = (float*)(smem_raw + 65792);             // 4*256 f32
    float* ysh = wsh + 4 * 256;                          // 4*256 f32
    float* Gsh = ysh + 4 * 256;                          // 256
    float* Bsh = Gsh + 256;                              // 256
    float* lsh = Bsh + 256;                              // 128
    _Float16* Psh = (_Float16*)(lsh + 128);              // 4*128 halves

    const int h = blockIdx.x, grp = blockIdx.y;
    const int tid = threadIdx.x, lane = tid & 63, w = tid >> 6;

    // stage K[h] -> fp16 cg-blocked
    for (int i = tid; i < 256 * 32; i += 256) {
        const int row = i >> 5, d4 = i & 31;
        const float4 kv = *(const float4*)&kn[(row * NH + h) * HD + d4 * 4];
        h4 hv;
        hv.x = (_Float16)kv.x; hv.y = (_Float16)kv.y;
        hv.z = (_Float16)kv.z; hv.w = (_Float16)kv.w;
        *(h4*)&Ksh[(d4 >> 1) * CGSTR + row * 8 + (d4 & 1) * 4] = hv;
    }
    Gsh[tid] = G[tid * NH + h];
    Bsh[tid] = beta[tid * NH + h];
    if (tid < HD) lsh[tid] = lamb[h * HD + tid];
    __syncthreads();

    const int slot = grp * 4 + w;                        // 0..127
    float* myw = wsh + w * 256;
    float* myy = ysh + w * 256;
    _Float16* Pw = Psh + w * 128;
    const int d0 = lane * 2, d1 = lane * 2 + 1;
    const int cg = lane >> 2, jh = (lane & 3) * 2;       // pass2 addressing for d0
    const float2 l2 = *(const float2*)&lsh[d0];

    for (int j = 0; j < 2; j++) {
        const int t = (j == 0) ? slot : 255 - slot;
        const float Gt = Gsh[t];
        const int mmax = t >> 6;

        // precompute w_s(t) once per t
        for (int m = 0; m <= mmax; m++) {
            const int s = lane + 64 * m;
            if (s <= t) myw[s] = Bsh[s] * __expf(Gt - Gsh[s]);
        }

        const float2 b2 = *(const float2*)&qn[(t * NH + h) * HD + d0];
        float x0 = 0.f, x1 = 0.f;
        float r0 = b2.x, r1 = b2.y, p0 = r0, p1 = r1;
        {
            h2 ph; ph.x = (_Float16)p0; ph.y = (_Float16)p1;
            *(h2*)&Pw[d0] = ph;
        }
        float rs = wave_sum64(r0 * r0 + r1 * r1);

        for (int it = 0; it < NCG; it++) {
            // hoist p fragment (fp16)
            uint4 pf[16];
#pragma unroll
            for (int c = 0; c < 16; c++) pf[c] = *(const uint4*)&Pw[c * 8];
            // pass1: y_s = w_s * (k_s . p)
            for (int m = 0; m <= mmax; m++) {
                const int s = lane + 64 * m;
                float a = 0.f;
#pragma unroll
                for (int c = 0; c < 16; c++) {
                    const uint4 kv = *(const uint4*)&Ksh[c * CGSTR + s * 8];
                    a = fdot2(u2h(kv.x), u2h(pf[c].x), a);
                    a = fdot2(u2h(kv.y), u2h(pf[c].y), a);
                    a = fdot2(u2h(kv.z), u2h(pf[c].z), a);
                    a = fdot2(u2h(kv.w), u2h(pf[c].w), a);
                }
                if (s <= t) myy[s] = myw[s] * a;
            }
            // pass2: Ap = lamb.*p + sum_s y_s * k_s[d0,d1]
            float Ap0 = l2.x * p0, Ap1 = l2.y * p1;
            const int s4 = (t + 1) & ~3;
            int s = 0;
            for (; s < s4; s += 4) {
                const float4 y4 = *(const float4*)&myy[s];
#pragma unroll
                for (int q = 0; q < 4; q++) {
                    const h2 kh = u2h(*(const unsigned int*)&Ksh[cg * CGSTR + (s + q) * 8 + jh]);
                    const float yv = (q == 0) ? y4.x : (q == 1) ? y4.y : (q == 2) ? y4.z : y4.w;
                    Ap0 = fmaf(yv, (float)kh.x, Ap0);
                    Ap1 = fmaf(yv, (float)kh.y, Ap1);
                }
            }
            for (; s <= t; s++) {
                const float yv = myy[s];
                const h2 kh = u2h(*(const unsigned int*)&Ksh[cg * CGSTR + s * 8 + jh]);
                Ap0 = fmaf(yv, (float)kh.x, Ap0);
                Ap1 = fmaf(yv, (float)kh.y, Ap1);
            }
            const float pAp = wave_sum64(p0 * Ap0 + p1 * Ap1);
            const float alpha = rs / (pAp + 1e-12f);
            x0 = fmaf(alpha, p0, x0); x1 = fmaf(alpha, p1, x1);
            r0 = fmaf(-alpha, Ap0, r0); r1 = fmaf(-alpha, Ap1, r1);
            const float rsn = wave_sum64(r0 * r0 + r1 * r1);
            const float bcg = rsn / (rs + 1e-12f);
            p0 = fmaf(bcg, p0, r0); p1 = fmaf(bcg, p1, r1);
            rs = rsn;
            h2 ph; ph.x = (_Float16)p0; ph.y = (_Float16)p1;
            *(h2*)&Pw[d0] = ph;
        }

        // z_s = w_s * (k_s . x)
        {
            h2 xh; xh.x = (_Float16)x0; xh.y = (_Float16)x1;
            *(h2*)&Pw[d0] = xh;
        }
        uint4 pf[16];
#pragma unroll
        for (int c = 0; c < 16; c++) pf[c] = *(const uint4*)&Pw[c * 8];
        for (int m = 0; m <= mmax; m++) {
            const int s = lane + 64 * m;
            float a = 0.f;
#pragma unroll
            for (int c = 0; c < 16; c++) {
                const uint4 kv = *(const uint4*)&Ksh[c * CGSTR + s * 8];
                a = fdot2(u2h(kv.x), u2h(pf[c].x), a);
                a = fdot2(u2h(kv.y), u2h(pf[c].y), a);
                a = fdot2(u2h(kv.z), u2h(pf[c].z), a);
                a = fdot2(u2h(kv.w), u2h(pf[c].w), a);
            }
            if (s <= t) myy[s] = myw[s] * a;
        }
        // o_t = sum_s z_s * v_s  (V from global, L2-resident)
        float o0 = 0.f, o1 = 0.f;
#pragma unroll 4
        for (int s = 0; s <= t; s++) {
            const float zv = myy[s];
            const float2 v2 = *(const float2*)&vv[(s * NH + h) * HD + d0];
            o0 = fmaf(zv, v2.x, o0);
            o1 = fmaf(zv, v2.y, o1);
        }
        *(float2*)&o[(t * NH + h) * HD + d0] = make_float2(o0, o1);
    }
}

// ---------------- rmsnorm over D with weight ----------------
__global__ __launch_bounds__(128) void rmsnorm_kernel(const float* __restrict__ o,
                                                      const float* __restrict__ wt,
                                                      float* __restrict__ on)
{
    const int t = blockIdx.x, h = blockIdx.y, d = threadIdx.x;
    const float val = o[(t * NH + h) * HD + d];
    float v = val * val;
#pragma unroll
    for (int off = 32; off > 0; off >>= 1) v += __shfl_down(v, off, 64);
    __shared__ float red[2];
    if ((threadIdx.x & 63) == 0) red[threadIdx.x >> 6] = v;
    __syncthreads();
    const float mean = (red[0] + red[1]) * (1.f / HD);
    on[(t * NH + h) * HD + d] = val * rsqrtf(mean + 1e-5f) * wt[d];
}

extern "C" void kernel_launch(void* const* d_in, const int* in_sizes, int n_in,
                              void* d_out, int out_size, void* d_ws, size_t ws_size,
                              hipStream_t stream)
{
    (void)in_sizes; (void)n_in; (void)out_size; (void)ws_size;
    const float* x   = (const float*)d_in[0];
    const float* Wq  = (const float*)d_in[1];
    const float* Wk  = (const float*)d_in[2];
    const float* Wv  = (const float*)d_in[3];
    const float* Wa  = (const float*)d_in[4];
    const float* ba  = (const float*)d_in[5];
    const float* Wb  = (const float*)d_in[6];
    const float* bb  = (const float*)d_in[7];
    const float* cwq = (const float*)d_in[8];
    const float* cwk = (const float*)d_in[9];
    const float* lp  = (const float*)d_in[10];
    const float* onw = (const float*)d_in[11];
    const float* Wo  = (const float*)d_in[12];

    float* ws    = (float*)d_ws;
    float* q_pre = ws;
    float* k_pre = q_pre + 524288;
    float* v     = k_pre + 524288;
    float* qn    = v + 524288;
    float* kn    = qn + 524288;
    float* g     = kn + 524288;
    float* beta  = g + 4096;
    float* G     = beta + 4096;
    float* lamb  = G + 4096;
    float* o     = k_pre;               // alias: k_pre dead after conv
    float* onorm = q_pre;               // alias: q_pre dead after conv
    float* outp  = (float*)d_out;

    gemm_qkv_kernel<<<dim3(32, 4, 3), dim3(16, 16), 0, stream>>>(x, Wq, Wk, Wv, q_pre, k_pre, v);
    ab_kernel<<<dim3(TT), dim3(256), 0, stream>>>(x, Wa, ba, Wb, bb, g, beta);
    cumsum_kernel<<<1, 64, 0, stream>>>(g, G);
    lamb_kernel<<<8, 256, 0, stream>>>(lp, lamb);
    conv_silu_l2_kernel<<<dim3(TT, NH, 2), 128, 0, stream>>>(q_pre, k_pre, cwq, cwk, qn, kn);

    const size_t lds_bytes = 65792 + (4 * 256 + 4 * 256 + 256 + 256 + 128) * 4 + 4 * 128 * 2;
    (void)hipFuncSetAttribute((const void*)mesa_kernel,
                              hipFuncAttributeMaxDynamicSharedMemorySize, (int)lds_bytes);
    mesa_kernel<<<dim3(NH, 32), 256, lds_bytes, stream>>>(qn, kn, v, G, beta, lamb, o);

    rmsnorm_kernel<<<dim3(TT, NH), 128, 0, stream>>>(o, onw, onorm);
    gemm_out_kernel<<<dim3(32, 4, 1), dim3(16, 16), 0, stream>>>(onorm, Wo, outp);
}

// Round 3
// 568.484 us; speedup vs baseline: 2.3693x; 1.4374x over previous
//
#include <hip/hip_runtime.h>
#include <math.h>

#define TT 256
#define HIDDEN 2048
#define NH 16
#define HD 128
#define KDIM 2048
#define NCG 30

// fp16 cg-blocked K layout for mesa: [16 cg][256 row][8 halves]
#define CGSTR 2056

typedef _Float16 h2 __attribute__((ext_vector_type(2)));
typedef _Float16 h4 __attribute__((ext_vector_type(4)));
typedef _Float16 half8 __attribute__((ext_vector_type(8)));
typedef float floatx4 __attribute__((ext_vector_type(4)));

#if defined(__has_builtin)
#if __has_builtin(__builtin_amdgcn_fdot2)
#define HAVE_FDOT2 1
#endif
#endif

__device__ __forceinline__ h2 u2h(unsigned int u) { return __builtin_bit_cast(h2, u); }

__device__ __forceinline__ float fdot2(h2 a, h2 b, float c) {
#ifdef HAVE_FDOT2
    return __builtin_amdgcn_fdot2(a, b, c, false);
#else
    return fmaf((float)a.x, (float)b.x, fmaf((float)a.y, (float)b.y, c));
#endif
}

__device__ __forceinline__ float wave_sum64(float v) {
#pragma unroll
    for (int off = 32; off > 0; off >>= 1) v += __shfl_xor(v, off, 64);
    return v;
}

// ============ f16-MFMA GEMM: C[64,128-tile] = A[M,2048]@B[2048,2048-block] ============
// A: f32 row-major, staged to LDS f16 K-major (stride 40 halves, 2-way bank = free).
// B: f32 row-major, fragments gathered straight from global (L2-resident) + cvt.
// Wave w covers rows 0..63, cols w*32 (4 m-subtiles x 2 n-subtiles, 8 MFMA/K-step).
__global__ __launch_bounds__(256) void gemm_f16_kernel(
    const float* __restrict__ A,
    const float* __restrict__ B0, const float* __restrict__ B1, const float* __restrict__ B2,
    float* __restrict__ C0, float* __restrict__ C1, float* __restrict__ C2,
    int nTilesPerMat)
{
    __shared__ _Float16 Ash[64 * 40];

    const int tid = threadIdx.x, lane = tid & 63, w = tid >> 6;
    const int nt = blockIdx.x, mt = blockIdx.y;
    const int mat = nt / nTilesPerMat;
    const int n0 = (nt - mat * nTilesPerMat) * 128;
    const float* __restrict__ B = (mat == 0) ? B0 : (mat == 1) ? B1 : B2;
    float* __restrict__ C = (mat == 0) ? C0 : (mat == 1) ? C1 : C2;
    const int m0 = mt * 64;

    const int q = lane >> 4, l16 = lane & 15;
    const int ar = tid >> 2, ac = (tid & 3) * 8;       // A staging: row, col8
    const int bcol = n0 + w * 32 + l16;                // wave's B base column

    floatx4 acc[4][2] = {};

    // prefetch k0 = 0
    float4 pa0 = *(const float4*)&A[(m0 + ar) * KDIM + ac];
    float4 pa1 = *(const float4*)&A[(m0 + ar) * KDIM + ac + 4];
    float pbf[16];
    {
        const float* Bp = &B[(q * 8) * KDIM + bcol];
#pragma unroll
        for (int j = 0; j < 8; j++) { pbf[j] = Bp[j * KDIM]; pbf[8 + j] = Bp[j * KDIM + 16]; }
    }

    for (int k0 = 0; k0 < KDIM; k0 += 32) {
        __syncthreads();   // previous iteration's Ash readers done
        {
            half8 av;
            av[0] = (_Float16)pa0.x; av[1] = (_Float16)pa0.y;
            av[2] = (_Float16)pa0.z; av[3] = (_Float16)pa0.w;
            av[4] = (_Float16)pa1.x; av[5] = (_Float16)pa1.y;
            av[6] = (_Float16)pa1.z; av[7] = (_Float16)pa1.w;
            *(half8*)&Ash[ar * 40 + ac] = av;
        }
        half8 bh[2];
#pragma unroll
        for (int s = 0; s < 2; s++)
#pragma unroll
            for (int j = 0; j < 8; j++) bh[s][j] = (_Float16)pbf[s * 8 + j];
        __syncthreads();   // Ash ready

        if (k0 + 32 < KDIM) {  // software-pipeline next tile's global loads past the barrier
            pa0 = *(const float4*)&A[(m0 + ar) * KDIM + k0 + 32 + ac];
            pa1 = *(const float4*)&A[(m0 + ar) * KDIM + k0 + 32 + ac + 4];
            const float* Bp = &B[(k0 + 32 + q * 8) * KDIM + bcol];
#pragma unroll
            for (int j = 0; j < 8; j++) { pbf[j] = Bp[j * KDIM]; pbf[8 + j] = Bp[j * KDIM + 16]; }
        }

#pragma unroll
        for (int i = 0; i < 4; i++) {
            const half8 af = *(const half8*)&Ash[(i * 16 + l16) * 40 + q * 8];
            acc[i][0] = __builtin_amdgcn_mfma_f32_16x16x32_f16(af, bh[0], acc[i][0], 0, 0, 0);
            acc[i][1] = __builtin_amdgcn_mfma_f32_16x16x32_f16(af, bh[1], acc[i][1], 0, 0, 0);
        }
    }

    // C/D layout: col = lane&15, row = (lane>>4)*4 + reg
#pragma unroll
    for (int i = 0; i < 4; i++)
#pragma unroll
        for (int s = 0; s < 2; s++)
#pragma unroll
            for (int r = 0; r < 4; r++)
                C[(m0 + i * 16 + q * 4 + r) * KDIM + n0 + w * 32 + s * 16 + l16] = acc[i][s][r];
}

// ---------------- per-t small projections ----------------
__global__ __launch_bounds__(256) void ab_kernel(
    const float* __restrict__ X, const float* __restrict__ Wa, const float* __restrict__ ba,
    const float* __restrict__ Wb, const float* __restrict__ bb,
    float* __restrict__ g, float* __restrict__ beta)
{
    const int t = blockIdx.x;
    const int lane = threadIdx.x & 63, w = threadIdx.x >> 6;
    for (int oi = 0; oi < 8; oi++) {
        const int o = w * 8 + oi;
        const int h = o & 15, which = o >> 4;
        const float* W = which ? Wb : Wa;
        float acc = 0.f;
#pragma unroll 4
        for (int i = 0; i < 32; i++) {
            const int kk = lane + 64 * i;
            acc = fmaf(X[t * HIDDEN + kk], W[kk * NH + h], acc);
        }
        acc = wave_sum64(acc);
        if (lane == 0) {
            if (which == 0) {
                float z = acc + ba[h];
                g[t * NH + h] = fminf(z, 0.f) - log1pf(__expf(-fabsf(z)));
            } else {
                float z = acc + bb[h];
                beta[t * NH + h] = 1.f / (1.f + __expf(-z));
            }
        }
    }
}

__global__ __launch_bounds__(256) void cumsum_kernel(const float* __restrict__ g,
                                                     float* __restrict__ G) {
    __shared__ float gs[TT * NH];
    for (int i = threadIdx.x; i < TT * NH; i += 256) gs[i] = g[i];
    __syncthreads();
    if (threadIdx.x < NH) {
        const int h = threadIdx.x;
        float run = 0.f;
        for (int t = 0; t < TT; t++) { run += gs[t * NH + h]; gs[t * NH + h] = run; }
    }
    __syncthreads();
    for (int i = threadIdx.x; i < TT * NH; i += 256) G[i] = gs[i];
}

__global__ void lamb_kernel(const float* __restrict__ lp, float* __restrict__ lamb) {
    const int i = blockIdx.x * 256 + threadIdx.x;
    if (i < KDIM) {
        float x = lp[i];
        lamb[i] = fmaxf(x, 0.f) + log1pf(__expf(-fabsf(x))) + 0.25f;
    }
}

// ---------------- causal depthwise conv(4) + silu + per-head l2norm ----------------
__global__ __launch_bounds__(128) void conv_silu_l2_kernel(
    const float* __restrict__ q_pre, const float* __restrict__ k_pre,
    const float* __restrict__ cwq, const float* __restrict__ cwk,
    float* __restrict__ qn, float* __restrict__ kn)
{
    const int t = blockIdx.x, h = blockIdx.y, which = blockIdx.z;
    const int d = threadIdx.x;
    const int c = h * HD + d;
    const float* pre = which ? k_pre : q_pre;
    const float* cw  = which ? cwk : cwq;
    float y = 0.f;
#pragma unroll
    for (int i = 0; i < 4; i++) {
        const int ts = t - 3 + i;
        if (ts >= 0) y = fmaf(pre[ts * KDIM + c], cw[c * 4 + i], y);
    }
    const float s = y / (1.f + __expf(-y));
    float v = s * s;
#pragma unroll
    for (int off = 32; off > 0; off >>= 1) v += __shfl_down(v, off, 64);
    __shared__ float red[2];
    if ((threadIdx.x & 63) == 0) red[threadIdx.x >> 6] = v;
    __syncthreads();
    const float sum = red[0] + red[1];
    float* dst = which ? kn : qn;
    dst[t * KDIM + c] = s * rsqrtf(sum + 1e-6f);
}

// ---------------- mesa recurrence (unchanged from round 2) ----------------
__global__ __launch_bounds__(256) void mesa_kernel(
    const float* __restrict__ qn, const float* __restrict__ kn, const float* __restrict__ vv,
    const float* __restrict__ G, const float* __restrict__ beta, const float* __restrict__ lamb,
    float* __restrict__ o)
{
    extern __shared__ char smem_raw[];
    _Float16* Ksh = (_Float16*)smem_raw;                 // 16*2056 halves = 65792 B
    float* wsh = (float*)(smem_raw + 65792);             // 4*256 f32
    float* ysh = wsh + 4 * 256;                          // 4*256 f32
    float* Gsh = ysh + 4 * 256;                          // 256
    float* Bsh = Gsh + 256;                              // 256
    float* lsh = Bsh + 256;                              // 128
    _Float16* Psh = (_Float16*)(lsh + 128);              // 4*128 halves

    const int h = blockIdx.x, grp = blockIdx.y;
    const int tid = threadIdx.x, lane = tid & 63, w = tid >> 6;

    for (int i = tid; i < 256 * 32; i += 256) {
        const int row = i >> 5, d4 = i & 31;
        const float4 kv = *(const float4*)&kn[(row * NH + h) * HD + d4 * 4];
        h4 hv;
        hv.x = (_Float16)kv.x; hv.y = (_Float16)kv.y;
        hv.z = (_Float16)kv.z; hv.w = (_Float16)kv.w;
        *(h4*)&Ksh[(d4 >> 1) * CGSTR + row * 8 + (d4 & 1) * 4] = hv;
    }
    Gsh[tid] = G[tid * NH + h];
    Bsh[tid] = beta[tid * NH + h];
    if (tid < HD) lsh[tid] = lamb[h * HD + tid];
    __syncthreads();

    const int slot = grp * 4 + w;
    float* myw = wsh + w * 256;
    float* myy = ysh + w * 256;
    _Float16* Pw = Psh + w * 128;
    const int d0 = lane * 2, d1 = lane * 2 + 1;
    const int cg = lane >> 2, jh = (lane & 3) * 2;
    const float2 l2 = *(const float2*)&lsh[d0];

    for (int j = 0; j < 2; j++) {
        const int t = (j == 0) ? slot : 255 - slot;
        const float Gt = Gsh[t];
        const int mmax = t >> 6;

        for (int m = 0; m <= mmax; m++) {
            const int s = lane + 64 * m;
            if (s <= t) myw[s] = Bsh[s] * __expf(Gt - Gsh[s]);
        }

        const float2 b2 = *(const float2*)&qn[(t * NH + h) * HD + d0];
        float x0 = 0.f, x1 = 0.f;
        float r0 = b2.x, r1 = b2.y, p0 = r0, p1 = r1;
        {
            h2 ph; ph.x = (_Float16)p0; ph.y = (_Float16)p1;
            *(h2*)&Pw[d0] = ph;
        }
        float rs = wave_sum64(r0 * r0 + r1 * r1);

        for (int it = 0; it < NCG; it++) {
            uint4 pf[16];
#pragma unroll
            for (int c = 0; c < 16; c++) pf[c] = *(const uint4*)&Pw[c * 8];
            for (int m = 0; m <= mmax; m++) {
                const int s = lane + 64 * m;
                float a = 0.f;
#pragma unroll
                for (int c = 0; c < 16; c++) {
                    const uint4 kv = *(const uint4*)&Ksh[c * CGSTR + s * 8];
                    a = fdot2(u2h(kv.x), u2h(pf[c].x), a);
                    a = fdot2(u2h(kv.y), u2h(pf[c].y), a);
                    a = fdot2(u2h(kv.z), u2h(pf[c].z), a);
                    a = fdot2(u2h(kv.w), u2h(pf[c].w), a);
                }
                if (s <= t) myy[s] = myw[s] * a;
            }
            float Ap0 = l2.x * p0, Ap1 = l2.y * p1;
            const int s4 = (t + 1) & ~3;
            int s = 0;
            for (; s < s4; s += 4) {
                const float4 y4 = *(const float4*)&myy[s];
#pragma unroll
                for (int qq = 0; qq < 4; qq++) {
                    const h2 kh = u2h(*(const unsigned int*)&Ksh[cg * CGSTR + (s + qq) * 8 + jh]);
                    const float yv = (qq == 0) ? y4.x : (qq == 1) ? y4.y : (qq == 2) ? y4.z : y4.w;
                    Ap0 = fmaf(yv, (float)kh.x, Ap0);
                    Ap1 = fmaf(yv, (float)kh.y, Ap1);
                }
            }
            for (; s <= t; s++) {
                const float yv = myy[s];
                const h2 kh = u2h(*(const unsigned int*)&Ksh[cg * CGSTR + s * 8 + jh]);
                Ap0 = fmaf(yv, (float)kh.x, Ap0);
                Ap1 = fmaf(yv, (float)kh.y, Ap1);
            }
            const float pAp = wave_sum64(p0 * Ap0 + p1 * Ap1);
            const float alpha = rs / (pAp + 1e-12f);
            x0 = fmaf(alpha, p0, x0); x1 = fmaf(alpha, p1, x1);
            r0 = fmaf(-alpha, Ap0, r0); r1 = fmaf(-alpha, Ap1, r1);
            const float rsn = wave_sum64(r0 * r0 + r1 * r1);
            const float bcg = rsn / (rs + 1e-12f);
            p0 = fmaf(bcg, p0, r0); p1 = fmaf(bcg, p1, r1);
            rs = rsn;
            h2 ph; ph.x = (_Float16)p0; ph.y = (_Float16)p1;
            *(h2*)&Pw[d0] = ph;
        }

        {
            h2 xh; xh.x = (_Float16)x0; xh.y = (_Float16)x1;
            *(h2*)&Pw[d0] = xh;
        }
        uint4 pf[16];
#pragma unroll
        for (int c = 0; c < 16; c++) pf[c] = *(const uint4*)&Pw[c * 8];
        for (int m = 0; m <= mmax; m++) {
            const int s = lane + 64 * m;
            float a = 0.f;
#pragma unroll
            for (int c = 0; c < 16; c++) {
                const uint4 kv = *(const uint4*)&Ksh[c * CGSTR + s * 8];
                a = fdot2(u2h(kv.x), u2h(pf[c].x), a);
                a = fdot2(u2h(kv.y), u2h(pf[c].y), a);
                a = fdot2(u2h(kv.z), u2h(pf[c].z), a);
                a = fdot2(u2h(kv.w), u2h(pf[c].w), a);
            }
            if (s <= t) myy[s] = myw[s] * a;
        }
        float o0 = 0.f, o1 = 0.f;
#pragma unroll 4
        for (int s = 0; s <= t; s++) {
            const float zv = myy[s];
            const float2 v2 = *(const float2*)&vv[(s * NH + h) * HD + d0];
            o0 = fmaf(zv, v2.x, o0);
            o1 = fmaf(zv, v2.y, o1);
        }
        *(float2*)&o[(t * NH + h) * HD + d0] = make_float2(o0, o1);
    }
}

// ---------------- rmsnorm over D with weight ----------------
__global__ __launch_bounds__(128) void rmsnorm_kernel(const float* __restrict__ o,
                                                      const float* __restrict__ wt,
                                                      float* __restrict__ on)
{
    const int t = blockIdx.x, h = blockIdx.y, d = threadIdx.x;
    const float val = o[(t * NH + h) * HD + d];
    float v = val * val;
#pragma unroll
    for (int off = 32; off > 0; off >>= 1) v += __shfl_down(v, off, 64);
    __shared__ float red[2];
    if ((threadIdx.x & 63) == 0) red[threadIdx.x >> 6] = v;
    __syncthreads();
    const float mean = (red[0] + red[1]) * (1.f / HD);
    on[(t * NH + h) * HD + d] = val * rsqrtf(mean + 1e-5f) * wt[d];
}

extern "C" void kernel_launch(void* const* d_in, const int* in_sizes, int n_in,
                              void* d_out, int out_size, void* d_ws, size_t ws_size,
                              hipStream_t stream)
{
    (void)in_sizes; (void)n_in; (void)out_size; (void)ws_size;
    const float* x   = (const float*)d_in[0];
    const float* Wq  = (const float*)d_in[1];
    const float* Wk  = (const float*)d_in[2];
    const float* Wv  = (const float*)d_in[3];
    const float* Wa  = (const float*)d_in[4];
    const float* ba  = (const float*)d_in[5];
    const float* Wb  = (const float*)d_in[6];
    const float* bb  = (const float*)d_in[7];
    const float* cwq = (const float*)d_in[8];
    const float* cwk = (const float*)d_in[9];
    const float* lp  = (const float*)d_in[10];
    const float* onw = (const float*)d_in[11];
    const float* Wo  = (const float*)d_in[12];

    float* ws    = (float*)d_ws;
    float* q_pre = ws;
    float* k_pre = q_pre + 524288;
    float* v     = k_pre + 524288;
    float* qn    = v + 524288;
    float* kn    = qn + 524288;
    float* g     = kn + 524288;
    float* beta  = g + 4096;
    float* G     = beta + 4096;
    float* lamb  = G + 4096;
    float* o     = k_pre;               // alias: k_pre dead after conv
    float* onorm = q_pre;               // alias: q_pre dead after conv
    float* outp  = (float*)d_out;

    // QKV: 3 matrices x 16 n-tiles = 48 n-tiles, 4 m-tiles
    gemm_f16_kernel<<<dim3(48, 4), 256, 0, stream>>>(x, Wq, Wk, Wv, q_pre, k_pre, v, 16);
    ab_kernel<<<dim3(TT), dim3(256), 0, stream>>>(x, Wa, ba, Wb, bb, g, beta);
    cumsum_kernel<<<1, 256, 0, stream>>>(g, G);
    lamb_kernel<<<8, 256, 0, stream>>>(lp, lamb);
    conv_silu_l2_kernel<<<dim3(TT, NH, 2), 128, 0, stream>>>(q_pre, k_pre, cwq, cwk, qn, kn);

    const size_t lds_bytes = 65792 + (4 * 256 + 4 * 256 + 256 + 256 + 128) * 4 + 4 * 128 * 2;
    (void)hipFuncSetAttribute((const void*)mesa_kernel,
                              hipFuncAttributeMaxDynamicSharedMemorySize, (int)lds_bytes);
    mesa_kernel<<<dim3(NH, 32), 256, lds_bytes, stream>>>(qn, kn, v, G, beta, lamb, o);

    rmsnorm_kernel<<<dim3(TT, NH), 128, 0, stream>>>(o, onw, onorm);
    gemm_f16_kernel<<<dim3(16, 4), 256, 0, stream>>>(onorm, Wo, Wo, Wo, outp, outp, outp, 16);
}

// Round 4
// 359.128 us; speedup vs baseline: 3.7505x; 1.5830x over previous
//
#include <hip/hip_runtime.h>
#include <math.h>

#define TT 256
#define HIDDEN 2048
#define NH 16
#define HD 128
#define KDIM 2048
#define NCG 30

typedef _Float16 h2 __attribute__((ext_vector_type(2)));
typedef _Float16 h4 __attribute__((ext_vector_type(4)));
typedef _Float16 half8 __attribute__((ext_vector_type(8)));
typedef float floatx4 __attribute__((ext_vector_type(4)));

__device__ __forceinline__ float wave_sum64(float v) {
#pragma unroll
    for (int off = 32; off > 0; off >>= 1) v += __shfl_xor(v, off, 64);
    return v;
}

// ============ f16-MFMA GEMM: C[64,128-tile] = A[M,2048]@B[2048,2048-block] ============
__global__ __launch_bounds__(256) void gemm_f16_kernel(
    const float* __restrict__ A,
    const float* __restrict__ B0, const float* __restrict__ B1, const float* __restrict__ B2,
    float* __restrict__ C0, float* __restrict__ C1, float* __restrict__ C2,
    int nTilesPerMat)
{
    __shared__ _Float16 Ash[64 * 40];

    const int tid = threadIdx.x, lane = tid & 63, w = tid >> 6;
    const int nt = blockIdx.x, mt = blockIdx.y;
    const int mat = nt / nTilesPerMat;
    const int n0 = (nt - mat * nTilesPerMat) * 128;
    const float* __restrict__ B = (mat == 0) ? B0 : (mat == 1) ? B1 : B2;
    float* __restrict__ C = (mat == 0) ? C0 : (mat == 1) ? C1 : C2;
    const int m0 = mt * 64;

    const int q = lane >> 4, l16 = lane & 15;
    const int ar = tid >> 2, ac = (tid & 3) * 8;
    const int bcol = n0 + w * 32 + l16;

    floatx4 acc[4][2] = {};

    float4 pa0 = *(const float4*)&A[(m0 + ar) * KDIM + ac];
    float4 pa1 = *(const float4*)&A[(m0 + ar) * KDIM + ac + 4];
    float pbf[16];
    {
        const float* Bp = &B[(q * 8) * KDIM + bcol];
#pragma unroll
        for (int j = 0; j < 8; j++) { pbf[j] = Bp[j * KDIM]; pbf[8 + j] = Bp[j * KDIM + 16]; }
    }

    for (int k0 = 0; k0 < KDIM; k0 += 32) {
        __syncthreads();
        {
            half8 av;
            av[0] = (_Float16)pa0.x; av[1] = (_Float16)pa0.y;
            av[2] = (_Float16)pa0.z; av[3] = (_Float16)pa0.w;
            av[4] = (_Float16)pa1.x; av[5] = (_Float16)pa1.y;
            av[6] = (_Float16)pa1.z; av[7] = (_Float16)pa1.w;
            *(half8*)&Ash[ar * 40 + ac] = av;
        }
        half8 bh[2];
#pragma unroll
        for (int s = 0; s < 2; s++)
#pragma unroll
            for (int j = 0; j < 8; j++) bh[s][j] = (_Float16)pbf[s * 8 + j];
        __syncthreads();

        if (k0 + 32 < KDIM) {
            pa0 = *(const float4*)&A[(m0 + ar) * KDIM + k0 + 32 + ac];
            pa1 = *(const float4*)&A[(m0 + ar) * KDIM + k0 + 32 + ac + 4];
            const float* Bp = &B[(k0 + 32 + q * 8) * KDIM + bcol];
#pragma unroll
            for (int j = 0; j < 8; j++) { pbf[j] = Bp[j * KDIM]; pbf[8 + j] = Bp[j * KDIM + 16]; }
        }

#pragma unroll
        for (int i = 0; i < 4; i++) {
            const half8 af = *(const half8*)&Ash[(i * 16 + l16) * 40 + q * 8];
            acc[i][0] = __builtin_amdgcn_mfma_f32_16x16x32_f16(af, bh[0], acc[i][0], 0, 0, 0);
            acc[i][1] = __builtin_amdgcn_mfma_f32_16x16x32_f16(af, bh[1], acc[i][1], 0, 0, 0);
        }
    }

#pragma unroll
    for (int i = 0; i < 4; i++)
#pragma unroll
        for (int s = 0; s < 2; s++)
#pragma unroll
            for (int r = 0; r < 4; r++)
                C[(m0 + i * 16 + q * 4 + r) * KDIM + n0 + w * 32 + s * 16 + l16] = acc[i][s][r];
}

// ---------------- per-t small projections ----------------
__global__ __launch_bounds__(256) void ab_kernel(
    const float* __restrict__ X, const float* __restrict__ Wa, const float* __restrict__ ba,
    const float* __restrict__ Wb, const float* __restrict__ bb,
    float* __restrict__ g, float* __restrict__ beta)
{
    const int t = blockIdx.x;
    const int lane = threadIdx.x & 63, w = threadIdx.x >> 6;
    for (int oi = 0; oi < 8; oi++) {
        const int o = w * 8 + oi;
        const int h = o & 15, which = o >> 4;
        const float* W = which ? Wb : Wa;
        float acc = 0.f;
#pragma unroll 4
        for (int i = 0; i < 32; i++) {
            const int kk = lane + 64 * i;
            acc = fmaf(X[t * HIDDEN + kk], W[kk * NH + h], acc);
        }
        acc = wave_sum64(acc);
        if (lane == 0) {
            if (which == 0) {
                float z = acc + ba[h];
                g[t * NH + h] = fminf(z, 0.f) - log1pf(__expf(-fabsf(z)));
            } else {
                float z = acc + bb[h];
                beta[t * NH + h] = 1.f / (1.f + __expf(-z));
            }
        }
    }
}

__global__ __launch_bounds__(256) void cumsum_kernel(const float* __restrict__ g,
                                                     float* __restrict__ G) {
    __shared__ float gs[TT * NH];
    for (int i = threadIdx.x; i < TT * NH; i += 256) gs[i] = g[i];
    __syncthreads();
    if (threadIdx.x < NH) {
        const int h = threadIdx.x;
        float run = 0.f;
        for (int t = 0; t < TT; t++) { run += gs[t * NH + h]; gs[t * NH + h] = run; }
    }
    __syncthreads();
    for (int i = threadIdx.x; i < TT * NH; i += 256) G[i] = gs[i];
}

__global__ void lamb_kernel(const float* __restrict__ lp, float* __restrict__ lamb) {
    const int i = blockIdx.x * 256 + threadIdx.x;
    if (i < KDIM) {
        float x = lp[i];
        lamb[i] = fmaxf(x, 0.f) + log1pf(__expf(-fabsf(x))) + 0.25f;
    }
}

// ---------------- causal depthwise conv(4) + silu + per-head l2norm ----------------
__global__ __launch_bounds__(128) void conv_silu_l2_kernel(
    const float* __restrict__ q_pre, const float* __restrict__ k_pre,
    const float* __restrict__ cwq, const float* __restrict__ cwk,
    float* __restrict__ qn, float* __restrict__ kn)
{
    const int t = blockIdx.x, h = blockIdx.y, which = blockIdx.z;
    const int d = threadIdx.x;
    const int c = h * HD + d;
    const float* pre = which ? k_pre : q_pre;
    const float* cw  = which ? cwk : cwq;
    float y = 0.f;
#pragma unroll
    for (int i = 0; i < 4; i++) {
        const int ts = t - 3 + i;
        if (ts >= 0) y = fmaf(pre[ts * KDIM + c], cw[c * 4 + i], y);
    }
    const float s = y / (1.f + __expf(-y));
    float v = s * s;
#pragma unroll
    for (int off = 32; off > 0; off >>= 1) v += __shfl_down(v, off, 64);
    __shared__ float red[2];
    if ((threadIdx.x & 63) == 0) red[threadIdx.x >> 6] = v;
    __syncthreads();
    const float sum = red[0] + red[1];
    float* dst = which ? kn : qn;
    dst[t * KDIM + c] = s * rsqrtf(sum + 1e-6f);
}

// ================= MFMA-batched mesa CG =================
// Per WG: head h, t-block of 16 columns [t0, t0+16).  smax = s-range (mult of 64).
// Per iter:  S = K@P (MFMA, A=K frags in regs)   -> Y = W.*S  -> Ysh
//            AP = K^T@Y (MFMA, A=K^T frags in regs) + lamb.*P -> CG scalar updates
// CG state (x,r,p) per-lane in MFMA C-layout: d = w*32+ss*16+quad*4+r, t = t0+l16.
// Reductions over d = 8 in-lane + shfl_xor(16) + shfl_xor(32).
#define PSTR 136
#define YSTR 264

template<int SMAX>
__device__ __forceinline__ void mesa_cg(
    const float* __restrict__ qn, const float* __restrict__ kn, const float* __restrict__ vv,
    const float* __restrict__ G, const float* __restrict__ bet, const float* __restrict__ lamb,
    float* __restrict__ o, int h, int t0, _Float16* Psh, _Float16* Ysh)
{
    constexpr int NSUB1 = SMAX / 64;   // GEMM1 m-subtiles per wave (s rows)
    constexpr int NK2   = SMAX / 32;   // GEMM2 k-steps (s dim)

    const int tid = threadIdx.x, lane = tid & 63, w = tid >> 6;
    const int quad = lane >> 4, l16 = lane & 15;
    const int tmy = t0 + l16;
    const int dbase = w * 32;

    // ---- K1 frags: A = K, A[m=s][k=d] ----
    half8 K1[NSUB1][4];
#pragma unroll
    for (int ii = 0; ii < NSUB1; ii++) {
        const int srow = 16 * (w + 4 * ii) + l16;
        const float* kp = &kn[(srow * NH + h) * HD];
#pragma unroll
        for (int kk = 0; kk < 4; kk++) {
            const float4 a = *(const float4*)&kp[kk * 32 + quad * 8];
            const float4 b = *(const float4*)&kp[kk * 32 + quad * 8 + 4];
            half8 f;
            f[0] = (_Float16)a.x; f[1] = (_Float16)a.y; f[2] = (_Float16)a.z; f[3] = (_Float16)a.w;
            f[4] = (_Float16)b.x; f[5] = (_Float16)b.y; f[6] = (_Float16)b.z; f[7] = (_Float16)b.w;
            K1[ii][kk] = f;
        }
    }
    // ---- K2 frags: A = K^T, A[m=d][k=s] ----
    half8 K2[2][NK2];
#pragma unroll
    for (int ss = 0; ss < 2; ss++) {
        const int d = dbase + ss * 16 + l16;
#pragma unroll
        for (int kk = 0; kk < NK2; kk++) {
            half8 f;
#pragma unroll
            for (int jj = 0; jj < 8; jj++) {
                const int s = kk * 32 + quad * 8 + jj;
                f[jj] = (_Float16)kn[(s * NH + h) * HD + d];
            }
            K2[ss][kk] = f;
        }
    }
    // ---- W[s,t] = beta_s * exp(G_t - G_s) * [s<=t]  (iter-invariant, per-lane) ----
    const float Gt = G[tmy * NH + h];
    float Wm[NSUB1][4];
#pragma unroll
    for (int ii = 0; ii < NSUB1; ii++)
#pragma unroll
        for (int r = 0; r < 4; r++) {
            const int s = 16 * (w + 4 * ii) + quad * 4 + r;
            Wm[ii][r] = (s <= tmy) ? bet[s * NH + h] * __expf(Gt - G[s * NH + h]) : 0.f;
        }
    // ---- lamb, CG init ----
    float lam[8], xv[8], rv[8], pv[8];
#pragma unroll
    for (int ss = 0; ss < 2; ss++)
#pragma unroll
        for (int r = 0; r < 4; r++) {
            const int e = ss * 4 + r;
            const int d = dbase + ss * 16 + quad * 4 + r;
            lam[e] = lamb[h * HD + d];
            const float b = qn[(tmy * NH + h) * HD + d];
            xv[e] = 0.f; rv[e] = b; pv[e] = b;
        }
    float rs = 0.f;
#pragma unroll
    for (int e = 0; e < 8; e++) rs += rv[e] * rv[e];
    rs += __shfl_xor(rs, 16, 64); rs += __shfl_xor(rs, 32, 64);

    auto writeP = [&](const float* src) {
#pragma unroll
        for (int ss = 0; ss < 2; ss++) {
            h4 ph;
            ph.x = (_Float16)src[ss * 4 + 0]; ph.y = (_Float16)src[ss * 4 + 1];
            ph.z = (_Float16)src[ss * 4 + 2]; ph.w = (_Float16)src[ss * 4 + 3];
            *(h4*)&Psh[l16 * PSTR + dbase + ss * 16 + quad * 4] = ph;
        }
    };
    writeP(pv);

    for (int it = 0; it <= NCG; it++) {
        __syncthreads();                       // Psh ready
        // GEMM1: S = K @ P  (k-dim = 128)
        floatx4 acc1[NSUB1] = {};
#pragma unroll
        for (int kk = 0; kk < 4; kk++) {
            const half8 bf = *(const half8*)&Psh[l16 * PSTR + kk * 32 + quad * 8];
#pragma unroll
            for (int ii = 0; ii < NSUB1; ii++)
                acc1[ii] = __builtin_amdgcn_mfma_f32_16x16x32_f16(K1[ii][kk], bf, acc1[ii], 0, 0, 0);
        }
        // Y = W .* S -> Ysh  (f16, [t][s] layout)
#pragma unroll
        for (int ii = 0; ii < NSUB1; ii++) {
            h4 yh;
            yh.x = (_Float16)(Wm[ii][0] * acc1[ii][0]);
            yh.y = (_Float16)(Wm[ii][1] * acc1[ii][1]);
            yh.z = (_Float16)(Wm[ii][2] * acc1[ii][2]);
            yh.w = (_Float16)(Wm[ii][3] * acc1[ii][3]);
            *(h4*)&Ysh[l16 * YSTR + 16 * (w + 4 * ii) + quad * 4] = yh;
        }
        __syncthreads();                       // Ysh ready
        if (it == NCG) break;                  // Ysh now holds Z = W.*(K x)

        // GEMM2: AP = K^T @ Y  (k-dim = SMAX)
        floatx4 acc2[2] = {};
#pragma unroll
        for (int kk = 0; kk < NK2; kk++) {
            const half8 bf = *(const half8*)&Ysh[l16 * YSTR + kk * 32 + quad * 8];
#pragma unroll
            for (int ss = 0; ss < 2; ss++)
                acc2[ss] = __builtin_amdgcn_mfma_f32_16x16x32_f16(K2[ss][kk], bf, acc2[ss], 0, 0, 0);
        }
        float Ap[8], pAp = 0.f;
#pragma unroll
        for (int ss = 0; ss < 2; ss++)
#pragma unroll
            for (int r = 0; r < 4; r++) {
                const int e = ss * 4 + r;
                Ap[e] = acc2[ss][r] + lam[e] * pv[e];
                pAp += pv[e] * Ap[e];
            }
        pAp += __shfl_xor(pAp, 16, 64); pAp += __shfl_xor(pAp, 32, 64);
        const float alpha = rs / (pAp + 1e-12f);
        float rsn = 0.f;
#pragma unroll
        for (int e = 0; e < 8; e++) {
            xv[e] = fmaf(alpha, pv[e], xv[e]);
            rv[e] = fmaf(-alpha, Ap[e], rv[e]);
            rsn += rv[e] * rv[e];
        }
        rsn += __shfl_xor(rsn, 16, 64); rsn += __shfl_xor(rsn, 32, 64);
        const float bcg = rsn / (rs + 1e-12f);
#pragma unroll
        for (int e = 0; e < 8; e++) pv[e] = fmaf(bcg, pv[e], rv[e]);
        rs = rsn;
        writeP(it == NCG - 1 ? xv : pv);       // final iter stages x for the Z pass
    }

    // O^T = Z^T @ V : A = Z^T from Ysh, B = V gathered from global (L2-resident)
    floatx4 accO[2] = {};
#pragma unroll
    for (int kk = 0; kk < NK2; kk++) {
        const half8 af = *(const half8*)&Ysh[l16 * YSTR + kk * 32 + quad * 8];
#pragma unroll
        for (int ss = 0; ss < 2; ss++) {
            half8 bf;
#pragma unroll
            for (int jj = 0; jj < 8; jj++) {
                const int s = kk * 32 + quad * 8 + jj;
                bf[jj] = (_Float16)vv[(s * NH + h) * HD + dbase + ss * 16 + l16];
            }
            accO[ss] = __builtin_amdgcn_mfma_f32_16x16x32_f16(af, bf, accO[ss], 0, 0, 0);
        }
    }
#pragma unroll
    for (int ss = 0; ss < 2; ss++)
#pragma unroll
        for (int r = 0; r < 4; r++)
            o[((t0 + quad * 4 + r) * NH + h) * HD + dbase + ss * 16 + l16] = accO[ss][r];
}

__global__ __launch_bounds__(256, 2) void mesa_kernel(
    const float* __restrict__ qn, const float* __restrict__ kn, const float* __restrict__ vv,
    const float* __restrict__ G, const float* __restrict__ bet, const float* __restrict__ lamb,
    float* __restrict__ o)
{
    __shared__ __align__(16) _Float16 Psh[16 * PSTR];
    __shared__ __align__(16) _Float16 Ysh[16 * YSTR];
    const int h = blockIdx.x, jb = blockIdx.y, t0 = jb * 16;
    switch (jb >> 2) {
        case 0:  mesa_cg<64> (qn, kn, vv, G, bet, lamb, o, h, t0, Psh, Ysh); break;
        case 1:  mesa_cg<128>(qn, kn, vv, G, bet, lamb, o, h, t0, Psh, Ysh); break;
        case 2:  mesa_cg<192>(qn, kn, vv, G, bet, lamb, o, h, t0, Psh, Ysh); break;
        default: mesa_cg<256>(qn, kn, vv, G, bet, lamb, o, h, t0, Psh, Ysh); break;
    }
}

// ---------------- rmsnorm over D with weight ----------------
__global__ __launch_bounds__(128) void rmsnorm_kernel(const float* __restrict__ o,
                                                      const float* __restrict__ wt,
                                                      float* __restrict__ on)
{
    const int t = blockIdx.x, h = blockIdx.y, d = threadIdx.x;
    const float val = o[(t * NH + h) * HD + d];
    float v = val * val;
#pragma unroll
    for (int off = 32; off > 0; off >>= 1) v += __shfl_down(v, off, 64);
    __shared__ float red[2];
    if ((threadIdx.x & 63) == 0) red[threadIdx.x >> 6] = v;
    __syncthreads();
    const float mean = (red[0] + red[1]) * (1.f / HD);
    on[(t * NH + h) * HD + d] = val * rsqrtf(mean + 1e-5f) * wt[d];
}

extern "C" void kernel_launch(void* const* d_in, const int* in_sizes, int n_in,
                              void* d_out, int out_size, void* d_ws, size_t ws_size,
                              hipStream_t stream)
{
    (void)in_sizes; (void)n_in; (void)out_size; (void)ws_size;
    const float* x   = (const float*)d_in[0];
    const float* Wq  = (const float*)d_in[1];
    const float* Wk  = (const float*)d_in[2];
    const float* Wv  = (const float*)d_in[3];
    const float* Wa  = (const float*)d_in[4];
    const float* ba  = (const float*)d_in[5];
    const float* Wb  = (const float*)d_in[6];
    const float* bb  = (const float*)d_in[7];
    const float* cwq = (const float*)d_in[8];
    const float* cwk = (const float*)d_in[9];
    const float* lp  = (const float*)d_in[10];
    const float* onw = (const float*)d_in[11];
    const float* Wo  = (const float*)d_in[12];

    float* ws    = (float*)d_ws;
    float* q_pre = ws;
    float* k_pre = q_pre + 524288;
    float* v     = k_pre + 524288;
    float* qn    = v + 524288;
    float* kn    = qn + 524288;
    float* g     = kn + 524288;
    float* beta  = g + 4096;
    float* G     = beta + 4096;
    float* lamb  = G + 4096;
    float* o     = k_pre;               // alias: k_pre dead after conv
    float* onorm = q_pre;               // alias: q_pre dead after conv
    float* outp  = (float*)d_out;

    gemm_f16_kernel<<<dim3(48, 4), 256, 0, stream>>>(x, Wq, Wk, Wv, q_pre, k_pre, v, 16);
    ab_kernel<<<dim3(TT), dim3(256), 0, stream>>>(x, Wa, ba, Wb, bb, g, beta);
    cumsum_kernel<<<1, 256, 0, stream>>>(g, G);
    lamb_kernel<<<8, 256, 0, stream>>>(lp, lamb);
    conv_silu_l2_kernel<<<dim3(TT, NH, 2), 128, 0, stream>>>(q_pre, k_pre, cwq, cwk, qn, kn);

    mesa_kernel<<<dim3(NH, 16), 256, 0, stream>>>(qn, kn, v, G, beta, lamb, o);

    rmsnorm_kernel<<<dim3(TT, NH), 128, 0, stream>>>(o, onw, onorm);
    gemm_f16_kernel<<<dim3(16, 4), 256, 0, stream>>>(onorm, Wo, Wo, Wo, outp, outp, outp, 16);
}

// Round 5
// 292.647 us; speedup vs baseline: 4.6025x; 1.2272x over previous
//
#include <hip/hip_runtime.h>
#include <math.h>

#define TT 256
#define HIDDEN 2048
#define NH 16
#define HD 128
#define KDIM 2048
#define NCG 30

typedef _Float16 h2 __attribute__((ext_vector_type(2)));
typedef _Float16 h4 __attribute__((ext_vector_type(4)));
typedef _Float16 half8 __attribute__((ext_vector_type(8)));
typedef float floatx4 __attribute__((ext_vector_type(4)));

__device__ __forceinline__ float wave_sum64(float v) {
#pragma unroll
    for (int off = 32; off > 0; off >>= 1) v += __shfl_xor(v, off, 64);
    return v;
}

// ============ one-time weight transpose+cvt: Wt[n][k] f16 from W[k][n] f32 ============
__global__ __launch_bounds__(256) void wtrans_kernel(
    const float* __restrict__ W0, const float* __restrict__ W1,
    const float* __restrict__ W2, const float* __restrict__ W3,
    _Float16* __restrict__ T0, _Float16* __restrict__ T1,
    _Float16* __restrict__ T2, _Float16* __restrict__ T3)
{
    __shared__ float tile[64][68];
    const int z = blockIdx.z;
    const float* __restrict__ W = (z == 0) ? W0 : (z == 1) ? W1 : (z == 2) ? W2 : W3;
    _Float16* __restrict__ T = (z == 0) ? T0 : (z == 1) ? T1 : (z == 2) ? T2 : T3;
    const int k0 = blockIdx.x * 64, n0 = blockIdx.y * 64;
    const int tid = threadIdx.x;
#pragma unroll
    for (int p = 0; p < 4; p++) {
        const int idx = p * 256 + tid;
        const int r = idx >> 4, c = (idx & 15) * 4;
        const float4 v = *(const float4*)&W[(k0 + r) * KDIM + n0 + c];
        tile[r][c] = v.x; tile[r][c + 1] = v.y; tile[r][c + 2] = v.z; tile[r][c + 3] = v.w;
    }
    __syncthreads();
    const int n = tid & 63, kc = (tid >> 6) * 16;
    half8 o0, o1;
#pragma unroll
    for (int j = 0; j < 8; j++) o0[j] = (_Float16)tile[kc + j][n];
#pragma unroll
    for (int j = 0; j < 8; j++) o1[j] = (_Float16)tile[kc + 8 + j][n];
    *(half8*)&T[(size_t)(n0 + n) * KDIM + k0 + kc] = o0;
    *(half8*)&T[(size_t)(n0 + n) * KDIM + k0 + kc + 8] = o1;
}

// Tab[32][2048] f32: rows 0-15 = Wa^T, 16-31 = Wb^T
__global__ __launch_bounds__(256) void wab_trans_kernel(
    const float* __restrict__ Wa, const float* __restrict__ Wb, float* __restrict__ Tab)
{
    const int b = blockIdx.x;
    const int h = threadIdx.x & 15, kl = threadIdx.x >> 4;
    for (int p = 0; p < 16; p++) {
        const int k = b * 256 + p * 16 + kl;
        Tab[h * KDIM + k] = Wa[k * NH + h];
        Tab[(16 + h) * KDIM + k] = Wb[k * NH + h];
    }
}

// ============ f16-MFMA GEMM: A f32 (LDS-staged f16), B = Wt[n][k] f16 direct ============
__global__ __launch_bounds__(256) void gemm_f16_kernel(
    const float* __restrict__ A,
    const _Float16* __restrict__ Bt0, const _Float16* __restrict__ Bt1,
    const _Float16* __restrict__ Bt2,
    float* __restrict__ C0, float* __restrict__ C1, float* __restrict__ C2,
    int nTilesPerMat)
{
    __shared__ _Float16 Ash[64 * 40];

    const int tid = threadIdx.x, lane = tid & 63, w = tid >> 6;
    const int nt = blockIdx.x, mt = blockIdx.y;
    const int mat = nt / nTilesPerMat;
    const int n0 = (nt - mat * nTilesPerMat) * 128;
    const _Float16* __restrict__ Bt = (mat == 0) ? Bt0 : (mat == 1) ? Bt1 : Bt2;
    float* __restrict__ C = (mat == 0) ? C0 : (mat == 1) ? C1 : C2;
    const int m0 = mt * 64;

    const int q = lane >> 4, l16 = lane & 15;
    const int ar = tid >> 2, ac = (tid & 3) * 8;
    const size_t brow0 = (size_t)(n0 + w * 32 + l16) * KDIM;
    const size_t brow1 = brow0 + (size_t)16 * KDIM;

    floatx4 acc[4][2] = {};

    float4 pa0 = *(const float4*)&A[(m0 + ar) * KDIM + ac];
    float4 pa1 = *(const float4*)&A[(m0 + ar) * KDIM + ac + 4];
    half8 pb0 = *(const half8*)&Bt[brow0 + q * 8];
    half8 pb1 = *(const half8*)&Bt[brow1 + q * 8];

    for (int k0 = 0; k0 < KDIM; k0 += 32) {
        __syncthreads();
        {
            half8 av;
            av[0] = (_Float16)pa0.x; av[1] = (_Float16)pa0.y;
            av[2] = (_Float16)pa0.z; av[3] = (_Float16)pa0.w;
            av[4] = (_Float16)pa1.x; av[5] = (_Float16)pa1.y;
            av[6] = (_Float16)pa1.z; av[7] = (_Float16)pa1.w;
            *(half8*)&Ash[ar * 40 + ac] = av;
        }
        const half8 b0 = pb0, b1 = pb1;
        __syncthreads();

        if (k0 + 32 < KDIM) {
            pa0 = *(const float4*)&A[(m0 + ar) * KDIM + k0 + 32 + ac];
            pa1 = *(const float4*)&A[(m0 + ar) * KDIM + k0 + 32 + ac + 4];
            pb0 = *(const half8*)&Bt[brow0 + k0 + 32 + q * 8];
            pb1 = *(const half8*)&Bt[brow1 + k0 + 32 + q * 8];
        }

#pragma unroll
        for (int i = 0; i < 4; i++) {
            const half8 af = *(const half8*)&Ash[(i * 16 + l16) * 40 + q * 8];
            acc[i][0] = __builtin_amdgcn_mfma_f32_16x16x32_f16(af, b0, acc[i][0], 0, 0, 0);
            acc[i][1] = __builtin_amdgcn_mfma_f32_16x16x32_f16(af, b1, acc[i][1], 0, 0, 0);
        }
    }

#pragma unroll
    for (int i = 0; i < 4; i++)
#pragma unroll
        for (int s = 0; s < 2; s++)
#pragma unroll
            for (int r = 0; r < 4; r++)
                C[(m0 + i * 16 + q * 4 + r) * KDIM + n0 + w * 32 + s * 16 + l16] = acc[i][s][r];
}

// ---------------- g/beta projections (coalesced via Tab) ----------------
__global__ __launch_bounds__(256) void ab_kernel(
    const float* __restrict__ X, const float* __restrict__ Tab,
    const float* __restrict__ ba, const float* __restrict__ bb,
    float* __restrict__ g, float* __restrict__ beta)
{
    const int t = blockIdx.x;
    const int lane = threadIdx.x & 63, w = threadIdx.x >> 6;
    for (int oi = 0; oi < 8; oi++) {
        const int o = w * 8 + oi;
        const int h = o & 15, which = o >> 4;
        float acc = 0.f;
#pragma unroll
        for (int i = 0; i < 8; i++) {
            const int kk = lane * 4 + i * 256;
            const float4 xv = *(const float4*)&X[t * HIDDEN + kk];
            const float4 wv = *(const float4*)&Tab[o * KDIM + kk];
            acc = fmaf(xv.x, wv.x, acc); acc = fmaf(xv.y, wv.y, acc);
            acc = fmaf(xv.z, wv.z, acc); acc = fmaf(xv.w, wv.w, acc);
        }
        acc = wave_sum64(acc);
        if (lane == 0) {
            if (which == 0) {
                const float z = acc + ba[h];
                g[t * NH + h] = fminf(z, 0.f) - log1pf(__expf(-fabsf(z)));
            } else {
                const float z = acc + bb[h];
                beta[t * NH + h] = 1.f / (1.f + __expf(-z));
            }
        }
    }
}

// ---------------- prep: cumsum(g) + lamb = softplus + 0.25 ----------------
__global__ __launch_bounds__(256) void prep_kernel(const float* __restrict__ g,
                                                   float* __restrict__ G,
                                                   const float* __restrict__ lp,
                                                   float* __restrict__ lamb)
{
    __shared__ float gs[TT * NH];
    const int tid = threadIdx.x;
    for (int i = tid; i < KDIM; i += 256) {
        const float x = lp[i];
        lamb[i] = fmaxf(x, 0.f) + log1pf(__expf(-fabsf(x))) + 0.25f;
    }
    for (int i = tid; i < TT * NH; i += 256) gs[i] = g[i];
    __syncthreads();
    if (tid < NH) {
        float run = 0.f;
        for (int t = 0; t < TT; t++) { run += gs[t * NH + tid]; gs[t * NH + tid] = run; }
    }
    __syncthreads();
    for (int i = tid; i < TT * NH; i += 256) G[i] = gs[i];
}

// ---------------- conv(4)+silu+l2norm, q&k fused per (t,h) ----------------
__global__ __launch_bounds__(256) void conv_silu_l2_kernel(
    const float* __restrict__ q_pre, const float* __restrict__ k_pre,
    const float* __restrict__ cwq, const float* __restrict__ cwk,
    float* __restrict__ qn, float* __restrict__ kn)
{
    const int t = blockIdx.x, h = blockIdx.y;
    const int which = threadIdx.x >> 7, d = threadIdx.x & 127;
    const int w = threadIdx.x >> 6;
    const int c = h * HD + d;
    const float* pre = which ? k_pre : q_pre;
    const float* cw  = which ? cwk : cwq;
    float y = 0.f;
#pragma unroll
    for (int i = 0; i < 4; i++) {
        const int ts = t - 3 + i;
        if (ts >= 0) y = fmaf(pre[ts * KDIM + c], cw[c * 4 + i], y);
    }
    const float s = y / (1.f + __expf(-y));
    float v = s * s;
#pragma unroll
    for (int off = 32; off > 0; off >>= 1) v += __shfl_down(v, off, 64);
    __shared__ float red[4];
    if ((threadIdx.x & 63) == 0) red[w] = v;
    __syncthreads();
    const float sum = red[which * 2] + red[which * 2 + 1];
    float* dst = which ? kn : qn;
    dst[t * KDIM + c] = s * rsqrtf(sum + 1e-6f);
}

// ================= MFMA-batched mesa CG (spill-free) + fused rmsnorm =================
// K1 frags (A=K) hoisted in registers; Kt (A=K^T) staged in LDS f16 [d][s].
#define KTSTR 264     // halves; 132 dwords = 4 mod 32 -> 2-way (free)
#define PSTR 136
#define YSTR 264
#define MESA_LDS (128 * KTSTR * 2 + 16 * PSTR * 2 + 16 * YSTR * 2 + 64 * 4)

template<int SMAX>
__device__ __forceinline__ void mesa_cg(
    const float* __restrict__ qn, const float* __restrict__ kn, const float* __restrict__ vv,
    const float* __restrict__ G, const float* __restrict__ bet, const float* __restrict__ lamb,
    const float* __restrict__ onw, float* __restrict__ out,
    int h, int t0, _Float16* Kt, _Float16* Psh, _Float16* Ysh, float* red)
{
    constexpr int NSUB1 = SMAX / 64;
    constexpr int NK2   = SMAX / 32;

    const int tid = threadIdx.x, lane = tid & 63, w = tid >> 6;
    const int quad = lane >> 4, l16 = lane & 15;
    const int tmy = t0 + l16;
    const int dbase = w * 32;

    // ---- stage Kt[d][s] f16 (coalesced reads, h4 writes) ----
    {
        const int sd = tid & 127, sg = tid >> 7;
        for (int s0 = 0; s0 < SMAX; s0 += 8) {
            const int sb = s0 + sg * 4;
            h4 kv;
#pragma unroll
            for (int j = 0; j < 4; j++) kv[j] = (_Float16)kn[((sb + j) * NH + h) * HD + sd];
            *(h4*)&Kt[sd * KTSTR + sb] = kv;
        }
    }

    // ---- K1 frags: A = K, A[m=s][k=d] (registers, iter-invariant) ----
    half8 K1[NSUB1][4];
#pragma unroll
    for (int ii = 0; ii < NSUB1; ii++) {
        const int srow = 16 * (w + 4 * ii) + l16;
        const float* kp = &kn[(srow * NH + h) * HD];
#pragma unroll
        for (int kk = 0; kk < 4; kk++) {
            const float4 a = *(const float4*)&kp[kk * 32 + quad * 8];
            const float4 b = *(const float4*)&kp[kk * 32 + quad * 8 + 4];
            half8 f;
            f[0] = (_Float16)a.x; f[1] = (_Float16)a.y; f[2] = (_Float16)a.z; f[3] = (_Float16)a.w;
            f[4] = (_Float16)b.x; f[5] = (_Float16)b.y; f[6] = (_Float16)b.z; f[7] = (_Float16)b.w;
            K1[ii][kk] = f;
        }
    }
    // ---- W[s,t] (iter-invariant, per-lane) ----
    const float Gt = G[tmy * NH + h];
    float Wm[NSUB1][4];
#pragma unroll
    for (int ii = 0; ii < NSUB1; ii++)
#pragma unroll
        for (int r = 0; r < 4; r++) {
            const int s = 16 * (w + 4 * ii) + quad * 4 + r;
            Wm[ii][r] = (s <= tmy) ? bet[s * NH + h] * __expf(Gt - G[s * NH + h]) : 0.f;
        }
    // ---- lamb, CG init ----
    float lam[8], xv[8], rv[8], pv[8];
#pragma unroll
    for (int ss = 0; ss < 2; ss++)
#pragma unroll
        for (int r = 0; r < 4; r++) {
            const int e = ss * 4 + r;
            const int d = dbase + ss * 16 + quad * 4 + r;
            lam[e] = lamb[h * HD + d];
            const float b = qn[(tmy * NH + h) * HD + d];
            xv[e] = 0.f; rv[e] = b; pv[e] = b;
        }
    float rs = 0.f;
#pragma unroll
    for (int e = 0; e < 8; e++) rs += rv[e] * rv[e];
    rs += __shfl_xor(rs, 16, 64); rs += __shfl_xor(rs, 32, 64);

    auto writeP = [&](const float* src) {
#pragma unroll
        for (int ss = 0; ss < 2; ss++) {
            h4 ph;
            ph.x = (_Float16)src[ss * 4 + 0]; ph.y = (_Float16)src[ss * 4 + 1];
            ph.z = (_Float16)src[ss * 4 + 2]; ph.w = (_Float16)src[ss * 4 + 3];
            *(h4*)&Psh[l16 * PSTR + dbase + ss * 16 + quad * 4] = ph;
        }
    };
    writeP(pv);

    for (int it = 0; it <= NCG; it++) {
        __syncthreads();                       // Psh (and Kt on first pass) ready
        // GEMM1: S = K @ P
        floatx4 acc1[NSUB1] = {};
#pragma unroll
        for (int kk = 0; kk < 4; kk++) {
            const half8 bf = *(const half8*)&Psh[l16 * PSTR + kk * 32 + quad * 8];
#pragma unroll
            for (int ii = 0; ii < NSUB1; ii++)
                acc1[ii] = __builtin_amdgcn_mfma_f32_16x16x32_f16(K1[ii][kk], bf, acc1[ii], 0, 0, 0);
        }
        // Y = W .* S -> Ysh [t][s]
#pragma unroll
        for (int ii = 0; ii < NSUB1; ii++) {
            h4 yh;
            yh.x = (_Float16)(Wm[ii][0] * acc1[ii][0]);
            yh.y = (_Float16)(Wm[ii][1] * acc1[ii][1]);
            yh.z = (_Float16)(Wm[ii][2] * acc1[ii][2]);
            yh.w = (_Float16)(Wm[ii][3] * acc1[ii][3]);
            *(h4*)&Ysh[l16 * YSTR + 16 * (w + 4 * ii) + quad * 4] = yh;
        }
        __syncthreads();                       // Ysh ready
        if (it == NCG) break;                  // Ysh now holds Z

        // GEMM2: AP = K^T @ Y  (A-frags from Kt LDS)
        floatx4 acc2[2] = {};
#pragma unroll
        for (int kk = 0; kk < NK2; kk++) {
            const half8 bf = *(const half8*)&Ysh[l16 * YSTR + kk * 32 + quad * 8];
#pragma unroll
            for (int ss = 0; ss < 2; ss++) {
                const half8 af = *(const half8*)&Kt[(dbase + ss * 16 + l16) * KTSTR + kk * 32 + quad * 8];
                acc2[ss] = __builtin_amdgcn_mfma_f32_16x16x32_f16(af, bf, acc2[ss], 0, 0, 0);
            }
        }
        float Ap[8], pAp = 0.f;
#pragma unroll
        for (int ss = 0; ss < 2; ss++)
#pragma unroll
            for (int r = 0; r < 4; r++) {
                const int e = ss * 4 + r;
                Ap[e] = acc2[ss][r] + lam[e] * pv[e];
                pAp += pv[e] * Ap[e];
            }
        pAp += __shfl_xor(pAp, 16, 64); pAp += __shfl_xor(pAp, 32, 64);
        const float alpha = rs / (pAp + 1e-12f);
        float rsn = 0.f;
#pragma unroll
        for (int e = 0; e < 8; e++) {
            xv[e] = fmaf(alpha, pv[e], xv[e]);
            rv[e] = fmaf(-alpha, Ap[e], rv[e]);
            rsn += rv[e] * rv[e];
        }
        rsn += __shfl_xor(rsn, 16, 64); rsn += __shfl_xor(rsn, 32, 64);
        const float bcg = rsn / (rs + 1e-12f);
#pragma unroll
        for (int e = 0; e < 8; e++) pv[e] = fmaf(bcg, pv[e], rv[e]);
        rs = rsn;
        writeP(it == NCG - 1 ? xv : pv);       // final iter stages x for Z pass
    }

    // O^T = Z^T @ V  (A from Ysh, B = V gathered f32->f16 from global)
    floatx4 accO[2] = {};
#pragma unroll
    for (int kk = 0; kk < NK2; kk++) {
        const half8 af = *(const half8*)&Ysh[l16 * YSTR + kk * 32 + quad * 8];
#pragma unroll
        for (int ss = 0; ss < 2; ss++) {
            half8 bf;
#pragma unroll
            for (int jj = 0; jj < 8; jj++) {
                const int s = kk * 32 + quad * 8 + jj;
                bf[jj] = (_Float16)vv[(s * NH + h) * HD + dbase + ss * 16 + l16];
            }
            accO[ss] = __builtin_amdgcn_mfma_f32_16x16x32_f16(af, bf, accO[ss], 0, 0, 0);
        }
    }

    // ---- fused rmsnorm over d: lane holds t = t0+quad*4+r, d = dbase+ss*16+l16 ----
    float part[4];
#pragma unroll
    for (int r = 0; r < 4; r++) {
        part[r] = accO[0][r] * accO[0][r] + accO[1][r] * accO[1][r];
#pragma unroll
        for (int off = 1; off < 16; off <<= 1) part[r] += __shfl_xor(part[r], off, 64);
    }
    if (l16 == 0) {
#pragma unroll
        for (int r = 0; r < 4; r++) red[w * 16 + quad * 4 + r] = part[r];
    }
    __syncthreads();
    const float w0 = onw[dbase + l16], w1 = onw[dbase + 16 + l16];
#pragma unroll
    for (int r = 0; r < 4; r++) {
        const int qr = quad * 4 + r;
        const float sumd = red[qr] + red[16 + qr] + red[32 + qr] + red[48 + qr];
        const float sc = rsqrtf(sumd * (1.f / HD) + 1e-5f);
        const int trow = ((t0 + qr) * NH + h) * HD;
        out[trow + dbase + l16] = accO[0][r] * sc * w0;
        out[trow + dbase + 16 + l16] = accO[1][r] * sc * w1;
    }
}

__global__ __launch_bounds__(256) void mesa_kernel(
    const float* __restrict__ qn, const float* __restrict__ kn, const float* __restrict__ vv,
    const float* __restrict__ G, const float* __restrict__ bet, const float* __restrict__ lamb,
    const float* __restrict__ onw, float* __restrict__ out)
{
    extern __shared__ char smem_raw[];
    _Float16* Kt  = (_Float16*)smem_raw;                         // 128*KTSTR halves
    _Float16* Psh = (_Float16*)(smem_raw + 128 * KTSTR * 2);     // 16*PSTR
    _Float16* Ysh = (_Float16*)(smem_raw + 128 * KTSTR * 2 + 16 * PSTR * 2);
    float* red = (float*)(smem_raw + 128 * KTSTR * 2 + 16 * PSTR * 2 + 16 * YSTR * 2);
    const int h = blockIdx.x, jb = blockIdx.y, t0 = jb * 16;
    switch (jb >> 2) {
        case 0:  mesa_cg<64> (qn, kn, vv, G, bet, lamb, onw, out, h, t0, Kt, Psh, Ysh, red); break;
        case 1:  mesa_cg<128>(qn, kn, vv, G, bet, lamb, onw, out, h, t0, Kt, Psh, Ysh, red); break;
        case 2:  mesa_cg<192>(qn, kn, vv, G, bet, lamb, onw, out, h, t0, Kt, Psh, Ysh, red); break;
        default: mesa_cg<256>(qn, kn, vv, G, bet, lamb, onw, out, h, t0, Kt, Psh, Ysh, red); break;
    }
}

extern "C" void kernel_launch(void* const* d_in, const int* in_sizes, int n_in,
                              void* d_out, int out_size, void* d_ws, size_t ws_size,
                              hipStream_t stream)
{
    (void)in_sizes; (void)n_in; (void)out_size; (void)ws_size;
    const float* x   = (const float*)d_in[0];
    const float* Wq  = (const float*)d_in[1];
    const float* Wk  = (const float*)d_in[2];
    const float* Wv  = (const float*)d_in[3];
    const float* Wa  = (const float*)d_in[4];
    const float* ba  = (const float*)d_in[5];
    const float* Wb  = (const float*)d_in[6];
    const float* bb  = (const float*)d_in[7];
    const float* cwq = (const float*)d_in[8];
    const float* cwk = (const float*)d_in[9];
    const float* lp  = (const float*)d_in[10];
    const float* onw = (const float*)d_in[11];
    const float* Wo  = (const float*)d_in[12];

    char* wsb = (char*)d_ws;
    float* q_pre = (float*)wsb;                          // 2 MB each
    float* k_pre = q_pre + 524288;
    float* v     = k_pre + 524288;
    float* qn    = v + 524288;
    float* kn    = qn + 524288;
    float* g     = kn + 524288;                          // 4096
    float* beta  = g + 4096;
    float* G     = beta + 4096;
    float* lamb  = G + 4096;                             // 2048
    // f16 transposed weights after the f32 region (16B aligned)
    size_t off = ((size_t)((char*)(lamb + 2048) - wsb) + 1023) & ~(size_t)1023;
    _Float16* WtQ = (_Float16*)(wsb + off);              // 8 MB each
    _Float16* WtK = WtQ + (size_t)KDIM * KDIM;
    _Float16* WtV = WtK + (size_t)KDIM * KDIM;
    _Float16* WtO = WtV + (size_t)KDIM * KDIM;
    float* Tab    = (float*)(WtO + (size_t)KDIM * KDIM); // 32*2048 f32
    float* onorm  = q_pre;                               // alias: dead after conv
    float* outp   = (float*)d_out;

    wtrans_kernel<<<dim3(32, 32, 4), 256, 0, stream>>>(Wq, Wk, Wv, Wo, WtQ, WtK, WtV, WtO);
    wab_trans_kernel<<<8, 256, 0, stream>>>(Wa, Wb, Tab);

    gemm_f16_kernel<<<dim3(48, 4), 256, 0, stream>>>(x, WtQ, WtK, WtV, q_pre, k_pre, v, 16);
    ab_kernel<<<dim3(TT), 256, 0, stream>>>(x, Tab, ba, bb, g, beta);
    prep_kernel<<<1, 256, 0, stream>>>(g, G, lp, lamb);
    conv_silu_l2_kernel<<<dim3(TT, NH), 256, 0, stream>>>(q_pre, k_pre, cwq, cwk, qn, kn);

    (void)hipFuncSetAttribute((const void*)mesa_kernel,
                              hipFuncAttributeMaxDynamicSharedMemorySize, MESA_LDS);
    mesa_kernel<<<dim3(NH, 16), 256, MESA_LDS, stream>>>(qn, kn, v, G, beta, lamb, onw, onorm);

    gemm_f16_kernel<<<dim3(16, 4), 256, 0, stream>>>(onorm, WtO, WtO, WtO, outp, outp, outp, 16);
}